// Round 1
// baseline (102.699 us; speedup 1.0000x reference)
//
#include <hip/hip_runtime.h>
#include <hip/hip_bf16.h>

typedef __attribute__((ext_vector_type(8))) short bf16x8;     // 8 bf16 = 4 VGPRs (MFMA A/B operand)
typedef __attribute__((ext_vector_type(4))) float f32x4;      // MFMA C/D
typedef __attribute__((ext_vector_type(8))) unsigned short ushort8;
typedef __attribute__((ext_vector_type(4))) unsigned short ushort4v;

constexpr int BB = 4096;   // batch B
constexpr int D  = 256;    // feature dim
constexpr int R2 = 8192;   // 2B rows of z
constexpr int NSPLIT = 8;  // column splits of the sim reduction
constexpr float SQRT2 = 1.41421356237309515f;
constexpr float E2 = 7.38905609893065f;  // exp(2) == exp(diag sim)

__device__ __forceinline__ unsigned short f2bf(float f) {
    __hip_bfloat16 h = __float2bfloat16(f);
    return *reinterpret_cast<unsigned short*>(&h);
}

// Kernel A: L2-normalize rows, scale by sqrt(2), store bf16 z[8192][256]; pos[k] = 2*cos(xi_k, xj_k).
// One wave per pair k.
__global__ __launch_bounds__(256) void norm_kernel(const float* __restrict__ xi,
                                                   const float* __restrict__ xj,
                                                   unsigned short* __restrict__ z,
                                                   float* __restrict__ pos) {
    const int wid = threadIdx.x >> 6, lane = threadIdx.x & 63;
    const int k = blockIdx.x * 4 + wid;
    const float4* a4 = reinterpret_cast<const float4*>(xi + (size_t)k * D);
    const float4* b4 = reinterpret_cast<const float4*>(xj + (size_t)k * D);
    float4 a = a4[lane], b = b4[lane];
    float ssi = a.x*a.x + a.y*a.y + a.z*a.z + a.w*a.w;
    float ssj = b.x*b.x + b.y*b.y + b.z*b.z + b.w*b.w;
    float dot = a.x*b.x + a.y*b.y + a.z*b.z + a.w*b.w;
#pragma unroll
    for (int off = 32; off; off >>= 1) {
        ssi += __shfl_xor(ssi, off);
        ssj += __shfl_xor(ssj, off);
        dot += __shfl_xor(dot, off);
    }
    const float inv_i = 1.0f / fmaxf(sqrtf(ssi), 1e-12f);
    const float inv_j = 1.0f / fmaxf(sqrtf(ssj), 1e-12f);
    const float si = inv_i * SQRT2, sj = inv_j * SQRT2;
    ushort4v zi = { f2bf(a.x*si), f2bf(a.y*si), f2bf(a.z*si), f2bf(a.w*si) };
    ushort4v zj = { f2bf(b.x*sj), f2bf(b.y*sj), f2bf(b.z*sj), f2bf(b.w*sj) };
    *reinterpret_cast<ushort4v*>(z + (size_t)k * D + lane*4)        = zi;
    *reinterpret_cast<ushort4v*>(z + (size_t)(k+BB) * D + lane*4)   = zj;
    if (lane == 0) pos[k] = dot * inv_i * inv_j * 2.0f;
}

// Kernel B: partial[split][r] = sum over this split's 1024 columns c of exp(z_r . z_c)
// (z pre-scaled by sqrt2 -> dot == 2*cos == sim/TEMP).
// Block: 4 waves, 128 rows (wave tile M=32). Col tiles of 64 staged in LDS.
__global__ __launch_bounds__(256) void sim_kernel(const unsigned short* __restrict__ z,
                                                  float* __restrict__ partial) {
    __shared__ unsigned short tb[64][D + 8];   // +8 ushort pad: row stride 528 B (== 16 mod 128) kills b128 conflicts
    const int wid = threadIdx.x >> 6, lane = threadIdx.x & 63;
    const int lrow = lane & 15, quad = lane >> 4;
    const int r0 = blockIdx.x * 128 + wid * 32;

    // A fragments for this wave's 32 rows, full K=256, held in registers (64 VGPRs).
    bf16x8 afrag[2][8];
#pragma unroll
    for (int m = 0; m < 2; ++m)
#pragma unroll
        for (int kk = 0; kk < 8; ++kk)
            afrag[m][kk] = *reinterpret_cast<const bf16x8*>(
                z + (size_t)(r0 + m*16 + lrow) * D + kk*32 + quad*8);

    float racc[2][4] = {{0.f,0.f,0.f,0.f},{0.f,0.f,0.f,0.f}};
    const int cbase = blockIdx.y * (R2 / NSPLIT);

    for (int ct = 0; ct < (R2 / NSPLIT) / 64; ++ct) {
        const int c0 = cbase + ct * 64;
        __syncthreads();   // previous tile fully consumed
#pragma unroll
        for (int i = 0; i < 8; ++i) {
            const int chunk = threadIdx.x + 256 * i;       // 2048 16B-chunks
            const int cr = chunk >> 5, ck = chunk & 31;
            *reinterpret_cast<ushort8*>(&tb[cr][ck*8]) =
                *reinterpret_cast<const ushort8*>(z + (size_t)(c0 + cr) * D + ck*8);
        }
        __syncthreads();
#pragma unroll
        for (int n = 0; n < 4; ++n) {
            bf16x8 bfrag[8];
#pragma unroll
            for (int kk = 0; kk < 8; ++kk)
                bfrag[kk] = *reinterpret_cast<const bf16x8*>(&tb[n*16 + lrow][kk*32 + quad*8]);
#pragma unroll
            for (int m = 0; m < 2; ++m) {
                f32x4 c = {0.f, 0.f, 0.f, 0.f};
#pragma unroll
                for (int kk = 0; kk < 8; ++kk)
                    c = __builtin_amdgcn_mfma_f32_16x16x32_bf16(afrag[m][kk], bfrag[kk], c, 0, 0, 0);
#pragma unroll
                for (int j = 0; j < 4; ++j)
                    racc[m][j] += __expf(c[j]);
            }
        }
    }

    // Row sums live across lanes sharing `quad`; reduce over lane bits 0-3 (the col index).
#pragma unroll
    for (int m = 0; m < 2; ++m)
#pragma unroll
        for (int j = 0; j < 4; ++j) {
            float v = racc[m][j];
            v += __shfl_xor(v, 1);
            v += __shfl_xor(v, 2);
            v += __shfl_xor(v, 4);
            v += __shfl_xor(v, 8);
            if (lrow == 0)
                partial[(size_t)blockIdx.y * R2 + r0 + m*16 + quad*4 + j] = v;
        }
}

// Kernel C: loss_r = log(exp(p_r) + S_r - e^2) - p_r ; out = mean.
__global__ __launch_bounds__(1024) void finalize_kernel(const float* __restrict__ partial,
                                                        const float* __restrict__ pos,
                                                        float* __restrict__ out) {
    __shared__ float wsum[16];
    const int tid = threadIdx.x;
    float lsum = 0.f;
    for (int r = tid; r < R2; r += 1024) {
        float S = 0.f;
#pragma unroll
        for (int s = 0; s < NSPLIT; ++s) S += partial[(size_t)s * R2 + r];
        const float p = pos[r & (BB - 1)];
        lsum += __logf(__expf(p) + S - E2) - p;
    }
#pragma unroll
    for (int off = 32; off; off >>= 1) lsum += __shfl_xor(lsum, off);
    if ((tid & 63) == 0) wsum[tid >> 6] = lsum;
    __syncthreads();
    if (tid == 0) {
        float t = 0.f;
#pragma unroll
        for (int i = 0; i < 16; ++i) t += wsum[i];
        out[0] = t / (float)R2;
    }
}

extern "C" void kernel_launch(void* const* d_in, const int* in_sizes, int n_in,
                              void* d_out, int out_size, void* d_ws, size_t ws_size,
                              hipStream_t stream) {
    (void)in_sizes; (void)n_in; (void)out_size; (void)ws_size;
    const float* xi = (const float*)d_in[0];
    const float* xj = (const float*)d_in[1];
    float* out = (float*)d_out;

    unsigned short* z = (unsigned short*)d_ws;                                   // 8192*256*2 = 4 MB
    float* partial = (float*)((char*)d_ws + (size_t)R2 * D * 2);                 // 8*8192*4 = 256 KB
    float* pos     = (float*)((char*)d_ws + (size_t)R2 * D * 2 + NSPLIT*R2*4);   // 16 KB

    norm_kernel<<<BB / 4, 256, 0, stream>>>(xi, xj, z, pos);
    sim_kernel<<<dim3(R2 / 128, NSPLIT), 256, 0, stream>>>(z, partial);
    finalize_kernel<<<1, 1024, 0, stream>>>(partial, pos, out);
}